// Round 2
// baseline (214.985 us; speedup 1.0000x reference)
//
#include <hip/hip_runtime.h>

typedef unsigned short u16;
typedef unsigned int   u32;

#define NB     20000   // batch of target nodes
#define SNB    25      // sampled neighbors (padded)
#define FEAT   256
#define K2     512     // 2*FEAT (concat dim)
#define OUTF   256

// Fused geometry (round 2): block = 16 nodes, 4 waves, 4 nodes/wave.
//   - 1250 blocks x 4 waves = 10,000 waves (vs 2,500 in round 1) -> gather TLP
//     back near the old wave-per-node agg kernel (which hit ~5 TB/s logical).
//   - LDS = As only: 16 x 520 x 2B = 16,640 B -> 7 blocks/CU (28 waves/CU),
//     so gather-phase blocks overlap MFMA-phase blocks on the same CU.
//   - B operand: no LDS staging. W-bf16 is 256 KB -> L2-resident; fragments
//     loaded straight from global with the proven mapping (row = wc+j*16+r16,
//     K-contiguous, 16 B/lane). 320 MB total from L2 ~= 9 us, hidden.
#define BM     16
#define NPW    4            // nodes per wave
#define LDA    520          // A row stride, elems (512 + 8 pad)
#define BK     32
#define NCHUNK (K2 / BK)    // 16

typedef __attribute__((ext_vector_type(8))) short short8;
typedef __attribute__((ext_vector_type(4))) float f32x4;

__device__ __forceinline__ u32 f2bf(float f) {
  union { u32 i; float f; } x; x.f = f;
  return (x.i + 0x7fffu + ((x.i >> 16) & 1u)) >> 16;  // RNE
}
__device__ __forceinline__ u32 pack2(float a, float b) {
  return f2bf(a) | (f2bf(b) << 16);
}

// ---------------------------------------------------------------------------
// w1 f32 -> bf16 (131072 elements). Halves the W fragment bytes in phase 2.
// ---------------------------------------------------------------------------
__global__ __launch_bounds__(256) void convw_kernel(
    const float* __restrict__ w_raw, u16* __restrict__ w_bf) {
  const int i = blockIdx.x * 256 + threadIdx.x;
  w_bf[i] = (u16)f2bf(w_raw[i]);
}

// ---------------------------------------------------------------------------
// Fused aggregate + GEMM, high-TLP variant:
//   phase 1: wave w gathers nodes [w*4, w*4+4): self row (bf16-RNE) and the
//            ragged neighbor mean, written straight to LDS As. Gather inner
//            loop identical to the proven agg_kernel (4 float4 gathers in
//            flight, __shfl-broadcast indices).
//   phase 2: out[16,256] = relu(As[16,512] @ W[256,512]^T). Wave w owns the
//            64-wide N-slice; A fragments from LDS (conflict-free: chunk
//            index (r+q)&7 uniform), B fragments direct from L2-resident W.
// 'combined' never touches HBM.
// ---------------------------------------------------------------------------
__global__ __launch_bounds__(256) void fused_kernel(
    const float* __restrict__ feats, const int* __restrict__ nodes,
    const int* __restrict__ neighs, const int* __restrict__ lens,
    const u16* __restrict__ W, float* __restrict__ C) {
  __shared__ u16 As[BM * LDA];

  const int tid   = threadIdx.x;
  const int wave  = tid >> 6;
  const int lane  = tid & 63;
  const int mbase = blockIdx.x * BM;

  // ---- phase 1: aggregate 4 nodes per wave into As ----
  for (int p = 0; p < NPW; ++p) {
    const int m = wave * NPW + p;         // local row 0..15
    const int b = mbase + m;              // global node (exact: 1250*16 = 20000)
    const int self = nodes[b];
    const int len  = lens[b];             // >= 1 guaranteed
    int myidx = (lane < SNB) ? neighs[b * SNB + lane] : 0;

    const float4 sv = ((const float4*)(feats + (size_t)self * FEAT))[lane];

    float4 a0 = {0.f, 0.f, 0.f, 0.f}, a1 = a0, a2 = a0, a3 = a0;
    int s = 0;
    for (; s + 4 <= len; s += 4) {        // len is wave-uniform -> cheap branch
      const int i0 = __shfl(myidx, s);
      const int i1 = __shfl(myidx, s + 1);
      const int i2 = __shfl(myidx, s + 2);
      const int i3 = __shfl(myidx, s + 3);
      const float4 v0 = ((const float4*)(feats + (size_t)i0 * FEAT))[lane];
      const float4 v1 = ((const float4*)(feats + (size_t)i1 * FEAT))[lane];
      const float4 v2 = ((const float4*)(feats + (size_t)i2 * FEAT))[lane];
      const float4 v3 = ((const float4*)(feats + (size_t)i3 * FEAT))[lane];
      a0.x += v0.x; a0.y += v0.y; a0.z += v0.z; a0.w += v0.w;
      a1.x += v1.x; a1.y += v1.y; a1.z += v1.z; a1.w += v1.w;
      a2.x += v2.x; a2.y += v2.y; a2.z += v2.z; a2.w += v2.w;
      a3.x += v3.x; a3.y += v3.y; a3.z += v3.z; a3.w += v3.w;
    }
    for (; s < len; ++s) {
      const int i0 = __shfl(myidx, s);
      const float4 v0 = ((const float4*)(feats + (size_t)i0 * FEAT))[lane];
      a0.x += v0.x; a0.y += v0.y; a0.z += v0.z; a0.w += v0.w;
    }
    const float inv = 1.f / (float)len;
    const float m0 = (a0.x + a1.x + a2.x + a3.x) * inv;
    const float m1 = (a0.y + a1.y + a2.y + a3.y) * inv;
    const float m2 = (a0.z + a1.z + a2.z + a3.z) * inv;
    const float m3 = (a0.w + a1.w + a2.w + a3.w) * inv;

    // combined[m, 0:256] = self, [256:512] = mean; bf16 RNE (same as before)
    uint2* arow = (uint2*)&As[m * LDA];   // byte base m*1040, 8B-aligned
    uint2 pe; pe.x = pack2(sv.x, sv.y); pe.y = pack2(sv.z, sv.w);
    arow[lane] = pe;                      // elems m*520 + lane*4
    uint2 pm; pm.x = pack2(m0, m1); pm.y = pack2(m2, m3);
    arow[64 + lane] = pm;                 // elems m*520 + 256 + lane*4
  }
  __syncthreads();                        // As complete

  // ---- phase 2: GEMM. wave -> N-slice [wave*64, wave*64+64) ----
  const int wc  = wave * 64;
  const int r16 = lane & 15;
  const int kq  = (lane >> 4) * 8;        // k-offset of this lane's quad

  f32x4 acc[4] = {};

#pragma unroll
  for (int kc = 0; kc < NCHUNK; ++kc) {
    const int k0 = kc * BK;
    const short8 af = *(const short8*)&As[r16 * LDA + k0 + kq];
#pragma unroll
    for (int j = 0; j < 4; ++j) {
      const short8 bf =
          *(const short8*)&W[(size_t)(wc + j * 16 + r16) * K2 + k0 + kq];
      acc[j] = __builtin_amdgcn_mfma_f32_16x16x32_bf16(af, bf, acc[j], 0, 0, 0);
    }
  }

  // ---- epilogue: C/D layout col = lane&15, row = (lane>>4)*4 + reg [m89] ----
#pragma unroll
  for (int r = 0; r < 4; ++r) {
    const int row = mbase + (lane >> 4) * 4 + r;   // always < 20000
#pragma unroll
    for (int j = 0; j < 4; ++j) {
      const int col = wc + j * 16 + r16;
      const float v = acc[j][r];
      C[(size_t)row * OUTF + col] = v > 0.f ? v : 0.f;
    }
  }
}

// ---------------------------------------------------------------------------
extern "C" void kernel_launch(void* const* d_in, const int* in_sizes, int n_in,
                              void* d_out, int out_size, void* d_ws, size_t ws_size,
                              hipStream_t stream) {
  const float* feats = (const float*)d_in[0];  // [100000, 256] f32
  const int* nodes   = (const int*)d_in[1];    // [20000]
  const int* neighs  = (const int*)d_in[2];    // [20000, 25]
  const int* lens    = (const int*)d_in[3];    // [20000]
  // d_in[4] = w0 — dead: layer-0 output is discarded by the reference loop.
  const float* w1    = (const float*)d_in[5];  // [256, 512] f32
  float* out = (float*)d_out;                  // [20000, 256] f32

  u16* w1bf = (u16*)d_ws;                      // [256, 512] bf16 (262,144 B)

  convw_kernel<<<512, 256, 0, stream>>>(w1, w1bf);
  fused_kernel<<<NB / BM, 256, 0, stream>>>(feats, nodes, neighs, lens, w1bf, out);
}

// Round 3
// 204.329 us; speedup vs baseline: 1.0522x; 1.0522x over previous
//
#include <hip/hip_runtime.h>

typedef unsigned short u16;
typedef unsigned int   u32;

#define NB     20000   // batch of target nodes
#define SNB    25      // sampled neighbors (padded)
#define FEAT   256
#define K2     512     // 2*FEAT (concat dim)
#define OUTF   256

// Round-3 geometry = round-1 (the faster cohort): block = 32 nodes, 4 waves,
// 8 nodes/wave, Bs staging (W passes L2 once per block: 625 x 262KB = 164 MB).
// LDS: As 32 x 520 x 2B = 33,280 B + Bs 256 x 40 x 2B = 20,480 B = 53,760 B.
// Change vs round 1: phase-1 gather unrolled 8-deep (8 float4 loads in flight
// per wave, was 4). Evidence: memory system is saturated+queueing (wave
// lifetime ~36us for ~20 rounds); standalone agg with ~128 outstanding
// loads/CU hit 5.8 TB/s effective vs fused's 3.8 at ~38 outstanding. Deeper
// unroll raises outstanding loads/CU ~2x and cuts dependent rounds/node
// from ~4.3 to ~2.6.
#define BM     32
#define NPW    8            // nodes per wave
#define LDA    520          // A row stride, elems (512 + 8 pad)
#define BK     32
#define LDB    40           // B row stride, elems (32 + 8 pad)
#define NCHUNK (K2 / BK)    // 16

typedef __attribute__((ext_vector_type(8))) short short8;
typedef __attribute__((ext_vector_type(4))) float f32x4;

__device__ __forceinline__ u32 f2bf(float f) {
  union { u32 i; float f; } x; x.f = f;
  return (x.i + 0x7fffu + ((x.i >> 16) & 1u)) >> 16;  // RNE
}
__device__ __forceinline__ u32 pack2(float a, float b) {
  return f2bf(a) | (f2bf(b) << 16);
}

// ---------------------------------------------------------------------------
// w1 f32 -> bf16 (131072 elements).
// ---------------------------------------------------------------------------
__global__ __launch_bounds__(256) void convw_kernel(
    const float* __restrict__ w_raw, u16* __restrict__ w_bf) {
  const int i = blockIdx.x * 256 + threadIdx.x;
  w_bf[i] = (u16)f2bf(w_raw[i]);
}

// ---------------------------------------------------------------------------
// Fused aggregate + GEMM (round-1 structure, 8-deep gather):
//   phase 1: wave w aggregates nodes [w*8, w*8+8): self row (bf16-RNE) and
//            ragged neighbor mean -> LDS As. 8 float4 gathers in flight.
//   phase 2: out[32,256] = relu(As[32,512] @ W[256,512]^T), W staged through
//            Bs in K=32 chunks, wave w owns N-slice [w*64, w*64+64).
// 'combined' never touches HBM.
// ---------------------------------------------------------------------------
__global__ __launch_bounds__(256) void fused_kernel(
    const float* __restrict__ feats, const int* __restrict__ nodes,
    const int* __restrict__ neighs, const int* __restrict__ lens,
    const u16* __restrict__ W, float* __restrict__ C) {
  __shared__ u16 As[BM * LDA];
  __shared__ u16 Bs[OUTF * LDB];

  const int tid   = threadIdx.x;
  const int wave  = tid >> 6;
  const int lane  = tid & 63;
  const int mbase = blockIdx.x * BM;

  // ---- prefetch B chunk 0 (independent of phase 1; overlaps the gathers) ---
  {
    const uint4* src = (const uint4*)(W + (size_t)tid * K2);  // row=tid, k=0..31
    uint4* dst = (uint4*)&Bs[tid * LDB];
#pragma unroll
    for (int c = 0; c < 4; ++c) dst[c] = src[c];
  }

  // ---- phase 1: aggregate 8 nodes per wave into As, 8 loads in flight ----
  for (int p = 0; p < NPW; ++p) {
    const int m = wave * NPW + p;         // local row 0..31
    const int b = mbase + m;              // global node (exact: 625*32 = 20000)
    const int self = nodes[b];
    const int len  = lens[b];             // >= 1 guaranteed
    int myidx = (lane < SNB) ? neighs[b * SNB + lane] : 0;

    const float4 sv = ((const float4*)(feats + (size_t)self * FEAT))[lane];

    float4 a0 = {0.f, 0.f, 0.f, 0.f}, a1 = a0, a2 = a0, a3 = a0;
    float4 a4 = a0, a5 = a0, a6 = a0, a7 = a0;
    int s = 0;
    for (; s + 8 <= len; s += 8) {        // len is wave-uniform -> cheap branch
      const int i0 = __shfl(myidx, s);
      const int i1 = __shfl(myidx, s + 1);
      const int i2 = __shfl(myidx, s + 2);
      const int i3 = __shfl(myidx, s + 3);
      const int i4 = __shfl(myidx, s + 4);
      const int i5 = __shfl(myidx, s + 5);
      const int i6 = __shfl(myidx, s + 6);
      const int i7 = __shfl(myidx, s + 7);
      const float4 v0 = ((const float4*)(feats + (size_t)i0 * FEAT))[lane];
      const float4 v1 = ((const float4*)(feats + (size_t)i1 * FEAT))[lane];
      const float4 v2 = ((const float4*)(feats + (size_t)i2 * FEAT))[lane];
      const float4 v3 = ((const float4*)(feats + (size_t)i3 * FEAT))[lane];
      const float4 v4 = ((const float4*)(feats + (size_t)i4 * FEAT))[lane];
      const float4 v5 = ((const float4*)(feats + (size_t)i5 * FEAT))[lane];
      const float4 v6 = ((const float4*)(feats + (size_t)i6 * FEAT))[lane];
      const float4 v7 = ((const float4*)(feats + (size_t)i7 * FEAT))[lane];
      a0.x += v0.x; a0.y += v0.y; a0.z += v0.z; a0.w += v0.w;
      a1.x += v1.x; a1.y += v1.y; a1.z += v1.z; a1.w += v1.w;
      a2.x += v2.x; a2.y += v2.y; a2.z += v2.z; a2.w += v2.w;
      a3.x += v3.x; a3.y += v3.y; a3.z += v3.z; a3.w += v3.w;
      a4.x += v4.x; a4.y += v4.y; a4.z += v4.z; a4.w += v4.w;
      a5.x += v5.x; a5.y += v5.y; a5.z += v5.z; a5.w += v5.w;
      a6.x += v6.x; a6.y += v6.y; a6.z += v6.z; a6.w += v6.w;
      a7.x += v7.x; a7.y += v7.y; a7.z += v7.z; a7.w += v7.w;
    }
    for (; s + 4 <= len; s += 4) {
      const int i0 = __shfl(myidx, s);
      const int i1 = __shfl(myidx, s + 1);
      const int i2 = __shfl(myidx, s + 2);
      const int i3 = __shfl(myidx, s + 3);
      const float4 v0 = ((const float4*)(feats + (size_t)i0 * FEAT))[lane];
      const float4 v1 = ((const float4*)(feats + (size_t)i1 * FEAT))[lane];
      const float4 v2 = ((const float4*)(feats + (size_t)i2 * FEAT))[lane];
      const float4 v3 = ((const float4*)(feats + (size_t)i3 * FEAT))[lane];
      a0.x += v0.x; a0.y += v0.y; a0.z += v0.z; a0.w += v0.w;
      a1.x += v1.x; a1.y += v1.y; a1.z += v1.z; a1.w += v1.w;
      a2.x += v2.x; a2.y += v2.y; a2.z += v2.z; a2.w += v2.w;
      a3.x += v3.x; a3.y += v3.y; a3.z += v3.z; a3.w += v3.w;
    }
    for (; s < len; ++s) {
      const int i0 = __shfl(myidx, s);
      const float4 v0 = ((const float4*)(feats + (size_t)i0 * FEAT))[lane];
      a0.x += v0.x; a0.y += v0.y; a0.z += v0.z; a0.w += v0.w;
    }
    a0.x += a4.x; a0.y += a4.y; a0.z += a4.z; a0.w += a4.w;
    a1.x += a5.x; a1.y += a5.y; a1.z += a5.z; a1.w += a5.w;
    a2.x += a6.x; a2.y += a6.y; a2.z += a6.z; a2.w += a6.w;
    a3.x += a7.x; a3.y += a7.y; a3.z += a7.z; a3.w += a7.w;
    const float inv = 1.f / (float)len;
    const float m0 = (a0.x + a1.x + a2.x + a3.x) * inv;
    const float m1 = (a0.y + a1.y + a2.y + a3.y) * inv;
    const float m2 = (a0.z + a1.z + a2.z + a3.z) * inv;
    const float m3 = (a0.w + a1.w + a2.w + a3.w) * inv;

    // combined[m, 0:256] = self, [256:512] = mean; bf16 RNE
    uint2* arow = (uint2*)&As[m * LDA];   // byte base m*1040, 8B-aligned
    uint2 pe; pe.x = pack2(sv.x, sv.y); pe.y = pack2(sv.z, sv.w);
    arow[lane] = pe;                      // elems m*520 + lane*4
    uint2 pm; pm.x = pack2(m0, m1); pm.y = pack2(m2, m3);
    arow[64 + lane] = pm;                 // elems m*520 + 256 + lane*4
  }
  __syncthreads();                        // As complete, Bs chunk 0 complete

  // ---- phase 2: GEMM. wave -> N-slice [wave*64, wave*64+64) ----
  const int wc  = wave * 64;
  const int r16 = lane & 15;
  const int kq  = (lane >> 4) * 8;        // k-offset of this lane's quad

  f32x4 acc[2][4] = {};

  for (int kc = 0; ; ) {
    const int k0 = kc * BK;
    short8 af[2], bf[4];
#pragma unroll
    for (int i = 0; i < 2; ++i)
      af[i] = *(const short8*)&As[(i * 16 + r16) * LDA + k0 + kq];
#pragma unroll
    for (int j = 0; j < 4; ++j)
      bf[j] = *(const short8*)&Bs[(wc + j * 16 + r16) * LDB + kq];

#pragma unroll
    for (int i = 0; i < 2; ++i)
#pragma unroll
      for (int j = 0; j < 4; ++j)
        acc[i][j] = __builtin_amdgcn_mfma_f32_16x16x32_bf16(af[i], bf[j],
                                                            acc[i][j], 0, 0, 0);
    if (++kc == NCHUNK) break;
    __syncthreads();   // all waves done reading old Bs (frags are in regs)
    {
      const uint4* src = (const uint4*)(W + (size_t)tid * K2 + kc * BK);
      uint4* dst = (uint4*)&Bs[tid * LDB];
#pragma unroll
      for (int c = 0; c < 4; ++c) dst[c] = src[c];
    }
    __syncthreads();   // next Bs chunk ready
  }

  // ---- epilogue: C/D layout col = lane&15, row = (lane>>4)*4 + reg [m89] ----
#pragma unroll
  for (int i = 0; i < 2; ++i)
#pragma unroll
    for (int r = 0; r < 4; ++r) {
      const int row = mbase + i * 16 + (lane >> 4) * 4 + r;  // always < 20000
#pragma unroll
      for (int j = 0; j < 4; ++j) {
        const int col = wc + j * 16 + (lane & 15);
        const float v = acc[i][j][r];
        C[(size_t)row * OUTF + col] = v > 0.f ? v : 0.f;
      }
    }
}

// ---------------------------------------------------------------------------
extern "C" void kernel_launch(void* const* d_in, const int* in_sizes, int n_in,
                              void* d_out, int out_size, void* d_ws, size_t ws_size,
                              hipStream_t stream) {
  const float* feats = (const float*)d_in[0];  // [100000, 256] f32
  const int* nodes   = (const int*)d_in[1];    // [20000]
  const int* neighs  = (const int*)d_in[2];    // [20000, 25]
  const int* lens    = (const int*)d_in[3];    // [20000]
  // d_in[4] = w0 — dead: layer-0 output is discarded by the reference loop.
  const float* w1    = (const float*)d_in[5];  // [256, 512] f32
  float* out = (float*)d_out;                  // [20000, 256] f32

  u16* w1bf = (u16*)d_ws;                      // [256, 512] bf16 (262,144 B)

  convw_kernel<<<512, 256, 0, stream>>>(w1, w1bf);
  fused_kernel<<<NB / BM, 256, 0, stream>>>(feats, nodes, neighs, lens, w1bf, out);
}